// Round 1
// baseline (115.462 us; speedup 1.0000x reference)
//
#include <hip/hip_runtime.h>
#include <math.h>

#define HW_PIX 65536   // 256*256
#define TDIM 512

__device__ __forceinline__ float wred64(float v) {
#pragma unroll
    for (int off = 32; off > 0; off >>= 1) v += __shfl_xor(v, off, 64);
    return v;
}

// Single fused kernel: each block redundantly computes the per-batch scalars
// (cheap: 128 KB L2-resident GEMV + 27 wave-distributed reductions), then
// streams its 1024-pixel slice. No inter-kernel dependency, one dispatch.
__global__ __launch_bounds__(256) void fused_kernel(
    const float* __restrict__ z,           // (16,3,256,256)
    const float* __restrict__ text_vec,    // (16,512)
    const float* __restrict__ text_proj_w, // (64,512)
    const float* __restrict__ text_proj_b, // (64)
    const float* __restrict__ z_proj_w,    // (64,3)
    const float* __restrict__ z_proj_b,    // (64)
    const float* __restrict__ out_w,       // (3,64)
    const float* __restrict__ out_bias,    // (3)
    const float* __restrict__ log_gamma,
    const float* __restrict__ alpha_p,
    const float* __restrict__ c_p,
    const float* __restrict__ wv,          // (3)
    float* __restrict__ out)               // (16,3,256,256)
{
    const int blk = blockIdx.x;
    const int b   = blk >> 6;          // 64 blocks per batch
    const int tid = threadIdx.x;

    __shared__ float t_sh[64];
    __shared__ float red[27];

    // ---- Stage A: t = text_vec[b] @ text_proj_w^T + text_proj_b ----
    {
        const int o = tid >> 2;        // output channel 0..63
        const int q = tid & 3;         // quarter of the 512-dot
        const float4* tv = (const float4*)(text_vec + (size_t)b * TDIM);
        const float4* wr = (const float4*)(text_proj_w + (size_t)o * TDIM);
        float acc = 0.f;
#pragma unroll 8
        for (int i = q * 32; i < q * 32 + 32; ++i) {
            float4 a = tv[i], w4 = wr[i];
            acc = fmaf(a.x, w4.x, fmaf(a.y, w4.y, fmaf(a.z, w4.z, fmaf(a.w, w4.w, acc))));
        }
        // combine the 4 quarters (consecutive lanes within a wave)
        acc += __shfl_xor(acc, 1, 64);
        acc += __shfl_xor(acc, 2, 64);
        if (q == 0) t_sh[o] = acc + text_proj_b[o];
    }
    __syncthreads();

    // ---- Stage B: 27 dot-reductions over o=0..63, 7 per wave (ILP chains) ----
    // red layout:
    //  0..4 : u0,u1,u2,s,tn
    //  5..10: G00,G01,G02,G11,G12,G22
    // 11..19: M row-major 3x3
    // 20..22: v0,v1,v2
    // 23..25: g0,g1,g2
    // 26   : bn
    {
        const int wave = tid >> 6, lane = tid & 63;
        const float t  = t_sh[lane];
        const float w0 = z_proj_w[lane * 3 + 0];
        const float w1 = z_proj_w[lane * 3 + 1];
        const float w2 = z_proj_w[lane * 3 + 2];
        const float zb = z_proj_b[lane];
        const float o0 = out_w[0 * 64 + lane];
        const float o1 = out_w[1 * 64 + lane];
        const float o2 = out_w[2 * 64 + lane];

        float pr[7];
        int n = 7;
        if (wave == 0) {
            pr[0] = w0 * t;  pr[1] = w1 * t;  pr[2] = w2 * t;
            pr[3] = zb * t;  pr[4] = t * t;   pr[5] = w0 * w0; pr[6] = w0 * w1;
        } else if (wave == 1) {
            pr[0] = w0 * w2; pr[1] = w1 * w1; pr[2] = w1 * w2;
            pr[3] = w2 * w2; pr[4] = o0 * w0; pr[5] = o0 * w1; pr[6] = o0 * w2;
        } else if (wave == 2) {
            pr[0] = o1 * w0; pr[1] = o1 * w1; pr[2] = o1 * w2;
            pr[3] = o2 * w0; pr[4] = o2 * w1; pr[5] = o2 * w2; pr[6] = o0 * zb;
        } else {
            pr[0] = o1 * zb; pr[1] = o2 * zb; pr[2] = w0 * zb;
            pr[3] = w1 * zb; pr[4] = w2 * zb; pr[5] = zb * zb; pr[6] = 0.f;
            n = 6;
        }
#pragma unroll
        for (int k = 0; k < 7; ++k) pr[k] = wred64(pr[k]);  // 7 independent chains
        if (lane == 0) {
            const int base = wave * 7;
            for (int k = 0; k < n; ++k) red[base + k] = pr[k];
        }
    }
    __syncthreads();

    // ---- Stage C: streaming fuse (identical math to verified kernel) ----
    const float u0 = red[0], u1 = red[1], u2 = red[2], s = red[3], tn = red[4];
    const float G00 = red[5], G01 = red[6], G02 = red[7];
    const float G11 = red[8], G12 = red[9], G22 = red[10];
    const float M00 = red[11], M01 = red[12], M02 = red[13];
    const float M10 = red[14], M11 = red[15], M12 = red[16];
    const float M20 = red[17], M21 = red[18], M22 = red[19];
    const float v0 = red[20], v1 = red[21], v2 = red[22];
    const float g0 = red[23], g1 = red[24], g2 = red[25], bn = red[26];

    const float gamma = __expf(log_gamma[0]);
    const float alpha = alpha_p[0], cc = c_p[0];
    const float w0 = wv[0], w1 = wv[1], w2 = wv[2];
    const float invw = 1.0f / (w0 + w1 + w2 + 1e-8f);
    const float ob0 = out_bias[0], ob1 = out_bias[1], ob2 = out_bias[2];

    const float e0 = g0 - u0, e1 = g1 - u1, e2 = g2 - u2;
    const float d0 = bn - 2.f * s + tn;

    const int p = ((blk & 63) << 10) + (tid << 2);   // 4 pixels/thread
    const float* zb = z + (size_t)b * 3 * HW_PIX + p;
    float4 q0 = *(const float4*)(zb);
    float4 q1 = *(const float4*)(zb + HW_PIX);
    float4 q2 = *(const float4*)(zb + 2 * HW_PIX);

    float X[4] = {q0.x, q0.y, q0.z, q0.w};
    float Y[4] = {q1.x, q1.y, q1.z, q1.w};
    float Z[4] = {q2.x, q2.y, q2.z, q2.w};
    float O0[4], O1[4], O2[4];

#pragma unroll
    for (int j = 0; j < 4; ++j) {
        const float x = X[j], y = Y[j], zc = Z[j];
        const float klin = fmaf(x, u0, fmaf(y, u1, fmaf(zc, u2, s)));
        const float quad = x * fmaf(2.f, fmaf(G01, y, G02 * zc), G00 * x)
                         + y * fmaf(2.f, G12 * zc, G11 * y)
                         + G22 * zc * zc;
        const float dist = quad + 2.f * fmaf(e0, x, fmaf(e1, y, e2 * zc)) + d0;
        const float krbf = __expf(-gamma * dist);
        float kp = fmaf(alpha, klin, cc);
        kp = kp * kp;
        const float k = (w0 * krbf + w1 * klin + w2 * kp) * invw;
        const float sig = 1.f / (1.f + __expf(-k));
        const float scale = 1.f + sig;

        const float m0 = fmaf(M00, x, fmaf(M01, y, fmaf(M02, zc, v0)));
        const float m1 = fmaf(M10, x, fmaf(M11, y, fmaf(M12, zc, v1)));
        const float m2 = fmaf(M20, x, fmaf(M21, y, fmaf(M22, zc, v2)));
        O0[j] = fmaf(scale, m0, ob0);
        O1[j] = fmaf(scale, m1, ob1);
        O2[j] = fmaf(scale, m2, ob2);
    }

    float* ob = out + (size_t)b * 3 * HW_PIX + p;
    *(float4*)(ob)              = make_float4(O0[0], O0[1], O0[2], O0[3]);
    *(float4*)(ob + HW_PIX)     = make_float4(O1[0], O1[1], O1[2], O1[3]);
    *(float4*)(ob + 2 * HW_PIX) = make_float4(O2[0], O2[1], O2[2], O2[3]);
}

extern "C" void kernel_launch(void* const* d_in, const int* in_sizes, int n_in,
                              void* d_out, int out_size, void* d_ws, size_t ws_size,
                              hipStream_t stream) {
    const float* z           = (const float*)d_in[0];
    const float* text_vec    = (const float*)d_in[1];
    const float* z_proj_w    = (const float*)d_in[2];
    const float* z_proj_b    = (const float*)d_in[3];
    const float* text_proj_w = (const float*)d_in[4];
    const float* text_proj_b = (const float*)d_in[5];
    const float* out_w       = (const float*)d_in[6];
    const float* out_b       = (const float*)d_in[7];
    const float* log_gamma   = (const float*)d_in[8];
    const float* alpha       = (const float*)d_in[9];
    const float* c           = (const float*)d_in[10];
    const float* w           = (const float*)d_in[11];
    float* out = (float*)d_out;
    (void)d_ws; (void)ws_size; (void)in_sizes; (void)n_in;

    fused_kernel<<<1024, 256, 0, stream>>>(z, text_vec, text_proj_w, text_proj_b,
                                           z_proj_w, z_proj_b, out_w, out_b,
                                           log_gamma, alpha, c, w, out);
}

// Round 2
// 94.259 us; speedup vs baseline: 1.2249x; 1.2249x over previous
//
#include <hip/hip_runtime.h>
#include <math.h>

#define HW_PIX 65536   // 256*256
#define TDIM 512

typedef float f4 __attribute__((ext_vector_type(4)));

__device__ __forceinline__ float wred64(float v) {
#pragma unroll
    for (int off = 32; off > 0; off >>= 1) v += __shfl_xor(v, off, 64);
    return v;
}

__device__ __forceinline__ f4 ld4(const float* p) { return *(const f4*)p; }
__device__ __forceinline__ void st4nt(float* p, f4 v) {
    __builtin_nontemporal_store(v, (f4*)p);
}

// ws layout (floats):
//  [b*8 + 0..4]  : u0,u1,u2,s, d0p(=tn-2s)          per batch b = 0..15
//  [128 + 0..31] : fully-baked constants (see prep block 16)
__global__ __launch_bounds__(256) void prep_kernel(
    const float* __restrict__ text_vec,    // (16,512)
    const float* __restrict__ text_proj_w, // (64,512)
    const float* __restrict__ text_proj_b, // (64)
    const float* __restrict__ z_proj_w,    // (64,3)
    const float* __restrict__ z_proj_b,    // (64)
    const float* __restrict__ out_w,       // (3,64)
    const float* __restrict__ out_bias,    // (3)
    const float* __restrict__ log_gamma,
    const float* __restrict__ alpha_p,
    const float* __restrict__ c_p,
    const float* __restrict__ wv,          // (3)
    float* __restrict__ ws)
{
    const int blk = blockIdx.x;
    const int tid = threadIdx.x;

    if (blk < 16) {
        // ---- per-batch: t = text_vec[b] @ text_proj_w^T + b, then 5 dots ----
        const int b = blk;
        const int o = tid >> 2;   // output channel 0..63
        const int q = tid & 3;    // quarter of the 512-dot
        const float4* tv = (const float4*)(text_vec + (size_t)b * TDIM);
        const float4* wr = (const float4*)(text_proj_w + (size_t)o * TDIM);
        float acc = 0.f;
#pragma unroll 8
        for (int i = q * 32; i < q * 32 + 32; ++i) {
            float4 a = tv[i], w4 = wr[i];
            acc = fmaf(a.x, w4.x, fmaf(a.y, w4.y, fmaf(a.z, w4.z, fmaf(a.w, w4.w, acc))));
        }
        acc += __shfl_xor(acc, 1, 64);
        acc += __shfl_xor(acc, 2, 64);

        __shared__ float t_sh[64];
        if (q == 0) t_sh[o] = acc + text_proj_b[o];
        __syncthreads();

        if (tid < 64) {
            const float t  = t_sh[tid];
            const float w0 = z_proj_w[tid * 3 + 0];
            const float w1 = z_proj_w[tid * 3 + 1];
            const float w2 = z_proj_w[tid * 3 + 2];
            const float zb = z_proj_b[tid];
            float u0 = wred64(w0 * t);
            float u1 = wred64(w1 * t);
            float u2 = wred64(w2 * t);
            float s  = wred64(zb * t);
            float tn = wred64(t * t);
            if (tid == 0) {
                float* pb = ws + b * 8;
                pb[0] = u0; pb[1] = u1; pb[2] = u2; pb[3] = s;
                pb[4] = fmaf(-2.f, s, tn);   // d0 partial (bn added in fuse)
            }
        }
    } else {
        // ---- weight-only constants, 22 reductions spread over 4 waves ----
        const int wave = tid >> 6, lane = tid & 63;
        const float w0 = z_proj_w[lane * 3 + 0];
        const float w1 = z_proj_w[lane * 3 + 1];
        const float w2 = z_proj_w[lane * 3 + 2];
        const float zb = z_proj_b[lane];
        const float o0 = out_w[0 * 64 + lane];
        const float o1 = out_w[1 * 64 + lane];
        const float o2 = out_w[2 * 64 + lane];
        float* c = ws + 128;
        // c layout: [0..3]=G00,G01,G02,G11  [4..7]=G12,G22,M00,M01
        //           [8..11]=M02,M10,M11,M12 [12..15]=M20,M21,M22,bn
        //           [16..19]=v0,v1,v2,ngamma [20..23]=g0,g1,g2,alpha
        //           [24..27]=cc,W0,W1,W2     [28..31]=ob0,ob1,ob2,pad
        if (wave == 0) {
            float r0 = wred64(w0 * w0), r1 = wred64(w0 * w1), r2 = wred64(w0 * w2);
            float r3 = wred64(w1 * w1), r4 = wred64(w1 * w2), r5 = wred64(w2 * w2);
            if (lane == 0) { c[0]=r0; c[1]=r1; c[2]=r2; c[3]=r3; c[4]=r4; c[5]=r5; }
        } else if (wave == 1) {
            float r0 = wred64(o0 * w0), r1 = wred64(o0 * w1), r2 = wred64(o0 * w2);
            float r3 = wred64(o1 * w0), r4 = wred64(o1 * w1), r5 = wred64(o1 * w2);
            if (lane == 0) { c[6]=r0; c[7]=r1; c[8]=r2; c[9]=r3; c[10]=r4; c[11]=r5; }
        } else if (wave == 2) {
            float r0 = wred64(o2 * w0), r1 = wred64(o2 * w1), r2 = wred64(o2 * w2);
            float r3 = wred64(zb * zb), r4 = wred64(o0 * zb), r5 = wred64(o1 * zb);
            if (lane == 0) { c[12]=r0; c[13]=r1; c[14]=r2; c[15]=r3; c[16]=r4; c[17]=r5; }
        } else {
            float r0 = wred64(o2 * zb), r1 = wred64(w0 * zb);
            float r2 = wred64(w1 * zb), r3 = wred64(w2 * zb);
            if (lane == 0) {
                c[18] = r0;                  // v2
                c[20] = r1; c[21] = r2; c[22] = r3;   // g
                c[19] = -__expf(log_gamma[0]);        // ngamma
                c[23] = alpha_p[0];
                c[24] = c_p[0];
                float a = wv[0], bb = wv[1], d = wv[2];
                float inv = 1.f / (a + bb + d + 1e-8f);
                c[25] = a * inv; c[26] = bb * inv; c[27] = d * inv;  // W0,W1,W2
                c[28] = out_bias[0]; c[29] = out_bias[1]; c[30] = out_bias[2];
                c[31] = 0.f;
            }
        }
    }
}

__global__ __launch_bounds__(256) void fuse_kernel(
    const float* __restrict__ z,   // (16,3,256,256)
    const float* __restrict__ ws,
    float* __restrict__ out)       // (16,3,256,256)
{
    const int blk = blockIdx.x;
    const int b   = blk >> 5;                               // 32 blocks per batch
    const int p   = ((blk & 31) << 11) + (threadIdx.x << 3); // 8 px/thread

    const f4* C4 = (const f4*)(ws + 128);
    const f4 f0 = C4[0], f1 = C4[1], f2 = C4[2], f3 = C4[3];
    const f4 f4v = C4[4], f5 = C4[5], f6 = C4[6], f7 = C4[7];
    const float G00=f0[0], G01=f0[1], G02=f0[2], G11=f0[3];
    const float G12=f1[0], G22=f1[1], M00=f1[2], M01=f1[3];
    const float M02=f2[0], M10=f2[1], M11=f2[2], M12=f2[3];
    const float M20=f3[0], M21=f3[1], M22=f3[2], bn =f3[3];
    const float v0=f4v[0], v1=f4v[1], v2=f4v[2], ngamma=f4v[3];
    const float g0=f5[0], g1=f5[1], g2=f5[2], alpha=f5[3];
    const float cc=f6[0], W0=f6[1], W1=f6[2], W2=f6[3];
    const float ob0=f7[0], ob1=f7[1], ob2=f7[2];

    const f4* pb4 = (const f4*)(ws + b * 8);
    const f4 pbA = pb4[0], pbB = pb4[1];
    const float u0=pbA[0], u1=pbA[1], u2=pbA[2], s=pbA[3];
    const float d0 = bn + pbB[0];
    const float e0 = g0 - u0, e1 = g1 - u1, e2 = g2 - u2;

    const float* zb = z + (size_t)b * 3 * HW_PIX + p;
    f4 a0 = ld4(zb),            a1 = ld4(zb + 4);
    f4 b0 = ld4(zb + HW_PIX),   b1 = ld4(zb + HW_PIX + 4);
    f4 c0 = ld4(zb + 2*HW_PIX), c1 = ld4(zb + 2*HW_PIX + 4);

    float X[8], Y[8], Z[8], O0[8], O1[8], O2[8];
#pragma unroll
    for (int j = 0; j < 4; ++j) {
        X[j] = a0[j]; X[j+4] = a1[j];
        Y[j] = b0[j]; Y[j+4] = b1[j];
        Z[j] = c0[j]; Z[j+4] = c1[j];
    }

#pragma unroll
    for (int j = 0; j < 8; ++j) {
        const float x = X[j], y = Y[j], zc = Z[j];
        const float klin = fmaf(x, u0, fmaf(y, u1, fmaf(zc, u2, s)));
        const float quad = x * fmaf(2.f, fmaf(G01, y, G02 * zc), G00 * x)
                         + y * fmaf(2.f, G12 * zc, G11 * y)
                         + G22 * zc * zc;
        const float dist = quad + 2.f * fmaf(e0, x, fmaf(e1, y, e2 * zc)) + d0;
        const float krbf = __expf(ngamma * dist);
        float kp = fmaf(alpha, klin, cc);
        kp = kp * kp;
        const float k = fmaf(W0, krbf, fmaf(W1, klin, W2 * kp));
        const float sig = 1.f / (1.f + __expf(-k));
        const float scale = 1.f + sig;

        const float m0 = fmaf(M00, x, fmaf(M01, y, fmaf(M02, zc, v0)));
        const float m1 = fmaf(M10, x, fmaf(M11, y, fmaf(M12, zc, v1)));
        const float m2 = fmaf(M20, x, fmaf(M21, y, fmaf(M22, zc, v2)));
        O0[j] = fmaf(scale, m0, ob0);
        O1[j] = fmaf(scale, m1, ob1);
        O2[j] = fmaf(scale, m2, ob2);
    }

    float* ob = out + (size_t)b * 3 * HW_PIX + p;
    f4 r;
    r[0]=O0[0]; r[1]=O0[1]; r[2]=O0[2]; r[3]=O0[3]; st4nt(ob, r);
    r[0]=O0[4]; r[1]=O0[5]; r[2]=O0[6]; r[3]=O0[7]; st4nt(ob + 4, r);
    r[0]=O1[0]; r[1]=O1[1]; r[2]=O1[2]; r[3]=O1[3]; st4nt(ob + HW_PIX, r);
    r[0]=O1[4]; r[1]=O1[5]; r[2]=O1[6]; r[3]=O1[7]; st4nt(ob + HW_PIX + 4, r);
    r[0]=O2[0]; r[1]=O2[1]; r[2]=O2[2]; r[3]=O2[3]; st4nt(ob + 2*HW_PIX, r);
    r[0]=O2[4]; r[1]=O2[5]; r[2]=O2[6]; r[3]=O2[7]; st4nt(ob + 2*HW_PIX + 4, r);
}

extern "C" void kernel_launch(void* const* d_in, const int* in_sizes, int n_in,
                              void* d_out, int out_size, void* d_ws, size_t ws_size,
                              hipStream_t stream) {
    const float* z           = (const float*)d_in[0];
    const float* text_vec    = (const float*)d_in[1];
    const float* z_proj_w    = (const float*)d_in[2];
    const float* z_proj_b    = (const float*)d_in[3];
    const float* text_proj_w = (const float*)d_in[4];
    const float* text_proj_b = (const float*)d_in[5];
    const float* out_w       = (const float*)d_in[6];
    const float* out_b       = (const float*)d_in[7];
    const float* log_gamma   = (const float*)d_in[8];
    const float* alpha       = (const float*)d_in[9];
    const float* c           = (const float*)d_in[10];
    const float* w           = (const float*)d_in[11];
    float* out = (float*)d_out;
    float* ws  = (float*)d_ws;
    (void)in_sizes; (void)n_in; (void)out_size; (void)ws_size;

    prep_kernel<<<17, 256, 0, stream>>>(text_vec, text_proj_w, text_proj_b,
                                        z_proj_w, z_proj_b, out_w, out_b,
                                        log_gamma, alpha, c, w, ws);
    fuse_kernel<<<512, 256, 0, stream>>>(z, ws, out);
}